// Round 12
// baseline (251.781 us; speedup 1.0000x reference)
//
#include <hip/hip_runtime.h>
#include <hip/hip_bf16.h>

typedef __attribute__((ext_vector_type(8))) short short8;   // 8 x bf16 (4 VGPRs) MFMA frag
typedef __attribute__((ext_vector_type(4))) float f32x4;    // MFMA accumulator
typedef __attribute__((ext_vector_type(4))) unsigned short us4;

#define GK 1024   // K dim of both GEMMs (= word dim)

// fast base-2 exp on gfx950 (v_exp_f32). __exp2f is CUDA-only (glibc macro collision).
#define EXP2F(x) __builtin_amdgcn_exp2f(x)

#define BARRIER() __builtin_amdgcn_s_barrier()
#define LGKM0()  do { asm volatile("s_waitcnt lgkmcnt(0)" ::: "memory"); \
                      __builtin_amdgcn_sched_barrier(0); } while (0)
#define VMC4()   asm volatile("s_waitcnt vmcnt(4)" ::: "memory")
#define VMC0()   asm volatile("s_waitcnt vmcnt(0)" ::: "memory")

// ---------- helpers ----------
__device__ __forceinline__ unsigned short f2bf(float f) {       // RNE f32->bf16
  unsigned int u = __float_as_uint(f);
  u += 0x7fffu + ((u >> 16) & 1u);
  return (unsigned short)(u >> 16);
}

__device__ __forceinline__ void gload16(const void* g, void* lds_base /*wave-uniform*/) {
  __builtin_amdgcn_global_load_lds(
      (const __attribute__((address_space(1))) unsigned int*)g,
      (__attribute__((address_space(3))) unsigned int*)lds_base, 16, 0, 0);
}

// ---------- kernel 1: cast f32 -> bf16 (x) ----------
__global__ void cast4_f32_bf16(const float* __restrict__ in, unsigned short* __restrict__ out, int n) {
  int i = (blockIdx.x * 256 + threadIdx.x) * 4;
  if (i >= n) return;
  float4 v = *(const float4*)(in + i);
  us4 o = { f2bf(v.x), f2bf(v.y), f2bf(v.z), f2bf(v.w) };
  *(us4*)(out + i) = o;
}

// ---------- kernel 2: transpose+cast W[K][N] f32 -> Wt[N][K] bf16 ----------
__global__ void transcast(const float* __restrict__ in, unsigned short* __restrict__ out, int K, int N) {
  __shared__ float t[32][33];
  int n0 = blockIdx.x * 32, k0 = blockIdx.y * 32;
  int tx = threadIdx.x, ty = threadIdx.y;
#pragma unroll
  for (int i = 0; i < 4; ++i)
    t[ty * 4 + i][tx] = in[(size_t)(k0 + ty * 4 + i) * N + n0 + tx];
  __syncthreads();
#pragma unroll
  for (int i = 0; i < 4; ++i)
    out[(size_t)(n0 + ty * 4 + i) * K + k0 + tx] = f2bf(t[tx][ty * 4 + i]);
}

// ================= 8-phase 256x256 GEMM (T3+T4+T2+T5), gemm1 only =================
// C[M][N] = A[M][1024] * Bt[N][1024]^T + bias, bf16 out.
// 512 thr / 8 waves (2Mx4N); per-wave 128x64 out; BK=64; LDS 128KB (2 bufs x (A+B) 32KB).
// Staging: global_load_lds, half-tiles of 128 rows (16 chunkgroups of 8 rows; wave w -> cg 2w,2w+1),
// source col pre-swizzled by row&7 (linear LDS dest, rule 21); reads use matching XOR.
// Schedule per iter (2 K-tiles t0->buf0, t1->buf1), phases:
//  P1: rdA(b0,m0)+rdB(b0,n0) | stage B0(t1)->b1 | bar lgkm0 prio MMA(0,0) bar
//  P2: rdA(b0,m1)            | stage B1(t1)->b1 | ... MMA(1,0)
//  P3: rdB(b0,n1)            | stage A0(t0+2)->b0 | ... MMA(1,1)
//  P4: --                    | stage A1(t0+2)->b0 | vmcnt(4) bar MMA(0,1) bar
//  P5-P8: mirror on buf1 (stage B(t0+2)->b0, A(t1+2)->b1), vmcnt(4) at P8.
// vmcnt(4) = 2 newest half-tiles (4 loads) may stay in flight; never 0 in steady loop.
__global__ __launch_bounds__(512, 2) void gemm8p(
    const unsigned short* __restrict__ A,
    const unsigned short* __restrict__ Bt,
    const float* __restrict__ bias,
    unsigned short* __restrict__ C, int M, int N)
{
  __shared__ __align__(16) unsigned short Asm[2][256 * 64];
  __shared__ __align__(16) unsigned short Bsm[2][256 * 64];

  int t = threadIdx.x, w = t >> 6, l = t & 63;
  int wm = w >> 2, wn = w & 3;
  int g = l >> 4, ln = l & 15, sw = ln & 7;

  // bijective 8-wide bm-supertile remap
  int flat = blockIdx.y * gridDim.x + blockIdx.x;
  int span = 8 * gridDim.y;
  int stripe = flat / span;
  int rr = flat - stripe * span;
  int bm = stripe * 8 + (rr & 7);
  int bn = rr >> 3;

  const unsigned short* Ablk = A + (size_t)(bm * 256) * GK;
  const unsigned short* Bblk = Bt + (size_t)(bn * 256) * GK;

  f32x4 acc[8][4] = {};
  short8 a[2][8];     // [ks][mf] both M-halves held
  short8 bq[2][2];    // [ks][nf-within-current-N-half]

  int rin = l >> 3;                       // row within 8-row chunkgroup
  int scol = ((l & 7) ^ (l >> 3)) * 8;    // pre-swizzled source col (elems)

#define SA(BUF, KT, HALF) do {                                                     \
    const unsigned short* _s = Ablk + (size_t)((HALF) * 128) * GK + (KT) * 64;     \
    _Pragma("unroll")                                                              \
    for (int _j = 0; _j < 2; ++_j) {                                               \
      int _cg = 2 * w + _j;                                                        \
      gload16(_s + (size_t)(_cg * 8 + rin) * GK + scol,                            \
              &Asm[BUF][(HALF) * 8192 + _cg * 512]);                               \
    } } while (0)
#define SBst(BUF, KT, HALF) do {                                                   \
    const unsigned short* _s = Bblk + (size_t)((HALF) * 128) * GK + (KT) * 64;     \
    _Pragma("unroll")                                                              \
    for (int _j = 0; _j < 2; ++_j) {                                               \
      int _cg = 2 * w + _j;                                                        \
      gload16(_s + (size_t)(_cg * 8 + rin) * GK + scol,                            \
              &Bsm[BUF][(HALF) * 8192 + _cg * 512]);                               \
    } } while (0)

#define RDA(BUF, MS) do {                                                          \
    _Pragma("unroll")                                                              \
    for (int _mf = 0; _mf < 4; ++_mf) {                                            \
      int _row = wm * 128 + ((MS) * 4 + _mf) * 16 + ln;                            \
      _Pragma("unroll")                                                            \
      for (int _ks = 0; _ks < 2; ++_ks)                                            \
        a[_ks][(MS) * 4 + _mf] =                                                   \
          *(const short8*)(&Asm[BUF][_row * 64 + (((_ks * 4 + g) ^ sw) * 8)]);     \
    } } while (0)
#define RDB(BUF, NS) do {                                                          \
    _Pragma("unroll")                                                              \
    for (int _nf = 0; _nf < 2; ++_nf) {                                            \
      int _row = wn * 64 + ((NS) * 2 + _nf) * 16 + ln;                             \
      _Pragma("unroll")                                                            \
      for (int _ks = 0; _ks < 2; ++_ks)                                            \
        bq[_ks][_nf] =                                                             \
          *(const short8*)(&Bsm[BUF][_row * 64 + (((_ks * 4 + g) ^ sw) * 8)]);     \
    } } while (0)

#define MMA(MS, NS) do {                                                           \
    __builtin_amdgcn_s_setprio(1);                                                 \
    _Pragma("unroll")                                                              \
    for (int _mf = 0; _mf < 4; ++_mf)                                              \
      _Pragma("unroll")                                                            \
      for (int _nf = 0; _nf < 2; ++_nf) {                                          \
        int _am = (MS) * 4 + _mf, _an = (NS) * 2 + _nf;                            \
        acc[_am][_an] = __builtin_amdgcn_mfma_f32_16x16x32_bf16(                   \
            a[0][_am], bq[0][_nf], acc[_am][_an], 0, 0, 0);                        \
        acc[_am][_an] = __builtin_amdgcn_mfma_f32_16x16x32_bf16(                   \
            a[1][_am], bq[1][_nf], acc[_am][_an], 0, 0, 0);                        \
      }                                                                            \
    __builtin_amdgcn_s_setprio(0); } while (0)

#define GEMM_ITER(T0, STEADY) do {                                                 \
    /* P1 */                                                                       \
    RDA(0, 0); RDB(0, 0); SBst(1, (T0) + 1, 0);                                    \
    BARRIER(); LGKM0(); MMA(0, 0); BARRIER();                                      \
    /* P2 */                                                                       \
    RDA(0, 1); SBst(1, (T0) + 1, 1);                                               \
    BARRIER(); LGKM0(); MMA(1, 0); BARRIER();                                      \
    /* P3 */                                                                       \
    RDB(0, 1); if (STEADY) SA(0, (T0) + 2, 0);                                     \
    BARRIER(); LGKM0(); MMA(1, 1); BARRIER();                                      \
    /* P4 */                                                                       \
    if (STEADY) { SA(0, (T0) + 2, 1); VMC4(); } else { VMC0(); }                   \
    BARRIER(); MMA(0, 1); BARRIER();                                               \
    /* P5 */                                                                       \
    RDA(1, 0); RDB(1, 0); if (STEADY) SBst(0, (T0) + 2, 0);                        \
    BARRIER(); LGKM0(); MMA(0, 0); BARRIER();                                      \
    /* P6 */                                                                       \
    RDA(1, 1); if (STEADY) SBst(0, (T0) + 2, 1);                                   \
    BARRIER(); LGKM0(); MMA(1, 0); BARRIER();                                      \
    /* P7 */                                                                       \
    RDB(1, 1); if (STEADY) SA(1, (T0) + 3, 0);                                     \
    BARRIER(); LGKM0(); MMA(1, 1); BARRIER();                                      \
    /* P8 */                                                                       \
    if (STEADY) { SA(1, (T0) + 3, 1); VMC4(); BARRIER(); }                         \
    MMA(0, 1);                                                                     \
    if (STEADY) BARRIER();                                                         \
  } while (0)

  // prologue: tile0 (buf0) fully + tile1 A-halves (buf1); tile1 B staged in iter0 P1/P2
  SA(0, 0, 0); SA(0, 0, 1); SBst(0, 0, 0); SBst(0, 0, 1);
  SA(1, 1, 0); SA(1, 1, 1);
  VMC4();            // tile0's 8 loads landed; tile1 A (4 newest) may fly
  BARRIER();

  for (int j = 0; j < 7; ++j) {
    GEMM_ITER(2 * j, 1);
  }
  GEMM_ITER(14, 0);    // final pair (tiles 14,15): no next-tile staging, drain at P4

  // epilogue: C/D layout col = lane&15, row = (lane>>4)*4 + reg
  int rowb = bm * 256 + wm * 128 + g * 4;
  int colb = bn * 256 + wn * 64 + ln;
#pragma unroll
  for (int nf = 0; nf < 4; ++nf) {
    int col = colb + nf * 16;
    float bv = bias[col];
#pragma unroll
    for (int mf = 0; mf < 8; ++mf) {
      int row = rowb + mf * 16;
#pragma unroll
      for (int r2 = 0; r2 < 4; ++r2)
        C[(size_t)(row + r2) * N + col] = f2bf(acc[mf][nf][r2] + bv);
    }
  }
#undef SA
#undef SBst
#undef RDA
#undef RDB
#undef MMA
#undef GEMM_ITER
}

// ---------- old 128^2 GEMM (kept for gemm2: N=1024 would under-fill 256^2 grid) ----------
template <int OUT_BF16>
__global__ __launch_bounds__(256) void gemm_nt(
    const unsigned short* __restrict__ A,
    const unsigned short* __restrict__ Bt,
    const float* __restrict__ bias,
    void* __restrict__ C, int M, int N)
{
  __shared__ __align__(16) unsigned short Asm[128 * 64];
  __shared__ __align__(16) unsigned short Bsm[128 * 64];

  int flat = blockIdx.y * gridDim.x + blockIdx.x;
  int span = 8 * gridDim.y;
  int stripe = flat / span;
  int r = flat - stripe * span;
  int bm = stripe * 8 + (r & 7);
  int bn = r >> 3;

  int t = threadIdx.x, w = t >> 6, l = t & 63;
  int wm = w >> 1, wn = w & 1;
  int g = l >> 4, ln = l & 15;

  const unsigned short* Ablk = A + (size_t)(bm * 128) * GK;
  const unsigned short* Bblk = Bt + (size_t)(bn * 128) * GK;

  f32x4 acc[4][4] = {};

  int srow_in = l >> 3;
  int scol = (((l & 7) ^ (l >> 3)) * 8);
  int swA = ln & 7;

  for (int kt = 0; kt < GK / 64; ++kt) {
    __syncthreads();
    int k0 = kt * 64 + scol;
#pragma unroll
    for (int j = 0; j < 4; ++j) {
      int chunk = w + 4 * j;
      int row = chunk * 8 + srow_in;
      gload16(Ablk + (size_t)row * GK + k0, Asm + chunk * 512);
      gload16(Bblk + (size_t)row * GK + k0, Bsm + chunk * 512);
    }
    __syncthreads();

#pragma unroll
    for (int ks = 0; ks < 2; ++ks) {
      int pc = ((ks * 4 + g) ^ swA) * 8;
      short8 af[4], bf[4];
#pragma unroll
      for (int mt = 0; mt < 4; ++mt) {
        int row = wm * 64 + ln + mt * 16;
        af[mt] = *(const short8*)(Asm + row * 64 + pc);
      }
#pragma unroll
      for (int nt = 0; nt < 4; ++nt) {
        int row = wn * 64 + ln + nt * 16;
        bf[nt] = *(const short8*)(Bsm + row * 64 + pc);
      }
#pragma unroll
      for (int mt = 0; mt < 4; ++mt)
#pragma unroll
        for (int nt = 0; nt < 4; ++nt)
          acc[mt][nt] = __builtin_amdgcn_mfma_f32_16x16x32_bf16(af[mt], bf[nt], acc[mt][nt], 0, 0, 0);
    }
  }

  int rowb = bm * 128 + wm * 64 + (g << 2);
  int colb = bn * 128 + wn * 64 + ln;
#pragma unroll
  for (int nt = 0; nt < 4; ++nt) {
    int col = colb + nt * 16;
    float bv = bias[col];
#pragma unroll
    for (int mt = 0; mt < 4; ++mt) {
      int row = rowb + mt * 16;
#pragma unroll
      for (int r2 = 0; r2 < 4; ++r2) {
        float v = acc[mt][nt][r2] + bv;
        if (OUT_BF16) ((unsigned short*)C)[(size_t)(row + r2) * N + col] = f2bf(v);
        else          ((float*)C)[(size_t)(row + r2) * N + col] = v;
      }
    }
  }
}

// ---------- kernel: transpose V slice of qkv -> Vt[(b*16+h)*64 + d][S] ----------
__global__ void transpose_v(const unsigned short* __restrict__ qkvb, unsigned short* __restrict__ Vt) {
  __shared__ __align__(16) unsigned short tile[64][72];   // [s][d], padded
  int blk = blockIdx.x;              // (b*16+h)*16 + s_tile
  int st = blk & 15, bh = blk >> 4, h = bh & 15, b = bh >> 4;
  int t = threadIdx.x;
  int srow = t >> 2, c0 = (t & 3) * 2;

  const unsigned short* src = qkvb + (size_t)(b * 1024 + st * 64 + srow) * 3072 + 2048 + h * 64;
#pragma unroll
  for (int j = 0; j < 2; ++j)
    *(short8*)(&tile[srow][(c0 + j) * 8]) = *(const short8*)(src + (c0 + j) * 8);
  __syncthreads();

  int d = t >> 2;
  unsigned short* dst = Vt + (size_t)(bh * 64 + d) * 1024 + st * 64;
#pragma unroll
  for (int j = 0; j < 2; ++j) {
    int s0 = (c0 + j) * 8;
    short8 v;
#pragma unroll
    for (int i = 0; i < 8; ++i) v[i] = tile[s0 + i][d];
    *(short8*)(dst + s0) = v;
  }
}

// ---------- flash attention v4: swapped-operand MFMA (lane-local softmax rows) ----------
__global__ __launch_bounds__(256) void attn(
    const unsigned short* __restrict__ qkv,  // [8192][3072] bf16
    const unsigned short* __restrict__ Vt,   // [(b*16+h)*64 + d][1024] bf16
    unsigned short* __restrict__ Ob)         // [8192][1024] bf16
{
  __shared__ __align__(16) unsigned short Ksm[2][64 * 64];  // [key][d] swizzled chunks
  __shared__ __align__(16) unsigned short Vsm[2][64 * 64];  // [d][key] swizzled chunks
  __shared__ __align__(16) unsigned short Psm[4][16 * 64];  // per-wave P [qrow][key] swizzled

  const float C1 = 0.18033688011112042f;    // 0.125 * log2(e)

  int t = threadIdx.x, w = t >> 6, l = t & 63;
  int g = l >> 4, ln = l & 15;
  int blk = blockIdx.x;
  int bh = blk & 127, pb = blk >> 7;        // same bh -> same XCD (round-robin dispatch)
  int h = bh & 15, b = bh >> 4;

  const unsigned short* Kg = qkv + (size_t)(b * 1024) * 3072 + 1024 + h * 64;
  const unsigned short* Vg = Vt + (size_t)(bh * 64) * 1024;
  unsigned short* P = Psm[w];

  int jrow = l >> 3;
  int jc   = l & 7;
  int cur = 0;

  auto stage = [&](int buf, int kt) {
#pragma unroll
    for (int jj = 0; jj < 2; ++jj) {
      int j = 2 * w + jj;
      int row = j * 8 + jrow;
      int sc = jc ^ (row & 7);
      gload16(Kg + (size_t)(kt * 64 + row) * 3072 + sc * 8, (unsigned short*)Ksm[buf] + j * 512);
      gload16(Vg + (size_t)row * 1024 + kt * 64 + sc * 8,   (unsigned short*)Vsm[buf] + j * 512);
    }
  };

  // P write slot (elements): row ln, keys nt*16+g*4..+3 -> chunk (nt*2+(g>>1))^(ln&7), half g&1
  int pwbase = ln * 64 + (g & 1) * 4;

#pragma unroll
  for (int half = 0; half < 2; ++half) {
    int qt = half ? (15 - pb) : pb;        // 64-row q-tile; iters qt+1 -> total 17/block

    const unsigned short* qbase =
        qkv + (size_t)(b * 1024 + qt * 64 + w * 16 + ln) * 3072 + h * 64 + g * 8;
    short8 qf0 = *(const short8*)(qbase);
    short8 qf1 = *(const short8*)(qbase + 32);

    f32x4 acc_o[4] = {};
    float m2 = -1.0e30f, lsum = 0.f;       // per-lane: row = qt*64 + w*16 + ln

    stage(cur, 0);
    __syncthreads();

    for (int kt = 0; kt <= qt; ++kt) {
      bool last = (kt == qt);
      if (!last) stage(cur ^ 1, kt + 1);    // prefetch next tile under compute

      // S^T = K Q^T: s[nt][r] = S[key = nt*16 + g*4 + r][qrow = ln]
      const unsigned short* Kb = Ksm[cur];
      f32x4 s[4] = {};
#pragma unroll
      for (int nt = 0; nt < 4; ++nt) {
        int krow = nt * 16 + ln;
        short8 k0 = *(const short8*)(Kb + krow * 64 + ((g ^ (krow & 7)) * 8));
        short8 k1 = *(const short8*)(Kb + krow * 64 + (((4 + g) ^ (krow & 7)) * 8));
        s[nt] = __builtin_amdgcn_mfma_f32_16x16x32_bf16(k0, qf0, s[nt], 0, 0, 0);
        s[nt] = __builtin_amdgcn_mfma_f32_16x16x32_bf16(k1, qf1, s[nt], 0, 0, 0);
      }

      // causal mask on diagonal tile: key (nt*16+g*4+r) > qrow (w*16+ln)
      if (last) {
        int qrow = w * 16 + ln;
#pragma unroll
        for (int nt = 0; nt < 4; ++nt)
#pragma unroll
          for (int r = 0; r < 4; ++r)
            if (nt * 16 + g * 4 + r > qrow) s[nt][r] = -1.0e9f;
      }

      // lane-local online softmax (row = ln), base-2 domain with folded 1/8 scale
      float mx0 = fmaxf(fmaxf(s[0][0], s[0][1]), fmaxf(s[0][2], s[0][3]));
      float mx1 = fmaxf(fmaxf(s[1][0], s[1][1]), fmaxf(s[1][2], s[1][3]));
      float mx2 = fmaxf(fmaxf(s[2][0], s[2][1]), fmaxf(s[2][2], s[2][3]));
      float mx3 = fmaxf(fmaxf(s[3][0], s[3][1]), fmaxf(s[3][2], s[3][3]));
      float mraw = fmaxf(fmaxf(mx0, mx1), fmaxf(mx2, mx3));
      mraw = fmaxf(mraw, __shfl_xor(mraw, 16));
      mraw = fmaxf(mraw, __shfl_xor(mraw, 32));
      float m2cand = mraw * C1;

      if (!__all(m2cand <= m2)) {           // T13 defer-max (exact): rescale only on growth
        float m2new = fmaxf(m2, m2cand);
        float corr = EXP2F(m2 - m2new);
        m2 = m2new;
        lsum *= corr;
#pragma unroll
        for (int nt = 0; nt < 4; ++nt)
#pragma unroll
          for (int r = 0; r < 4; ++r) acc_o[nt][r] *= corr;
      }

      float rs = 0.f;
#pragma unroll
      for (int nt = 0; nt < 4; ++nt)
#pragma unroll
        for (int r = 0; r < 4; ++r) {
          float p = EXP2F(fmaf(s[nt][r], C1, -m2));   // exp(s/8 - m)
          s[nt][r] = p;
          rs += p;
        }
      rs += __shfl_xor(rs, 16);
      rs += __shfl_xor(rs, 32);
      lsum += rs;

      // P -> per-wave swizzled LDS: one b64 per nt (4 contiguous keys of row ln)
#pragma unroll
      for (int nt = 0; nt < 4; ++nt) {
        us4 pk = { f2bf(s[nt][0]), f2bf(s[nt][1]), f2bf(s[nt][2]), f2bf(s[nt][3]) };
        *(us4*)(P + pwbase + (((nt * 2 + (g >> 1)) ^ (ln & 7)) * 8)) = pk;
      }
      short8 pa0 = *(const short8*)(P + ln * 64 + ((g ^ (ln & 7)) * 8));
      short8 pa1 = *(const short8*)(P + ln * 64 + (((4 + g) ^ (ln & 7)) * 8));

      // O^T = V^T P^T: acc_o[nt][r] = O[qrow=ln][d = nt*16 + g*4 + r]
      const unsigned short* Vb = Vsm[cur];
#pragma unroll
      for (int nt = 0; nt < 4; ++nt) {
        int vrow = nt * 16 + ln;
        short8 vb0 = *(const short8*)(Vb + vrow * 64 + ((g ^ (vrow & 7)) * 8));
        short8 vb1 = *(const short8*)(Vb + vrow * 64 + (((4 + g) ^ (vrow & 7)) * 8));
        acc_o[nt] = __builtin_amdgcn_mfma_f32_16x16x32_bf16(vb0, pa0, acc_o[nt], 0, 0, 0);
        acc_o[nt] = __builtin_amdgcn_mfma_f32_16x16x32_bf16(vb1, pa1, acc_o[nt], 0, 0, 0);
      }

      __syncthreads();                      // drains prefetch vmcnt + releases buffers
      cur ^= 1;
    }

    // normalize + store: lane owns row qt*64+w*16+ln, writes 4x 8B
    float inv = 1.0f / lsum;
    size_t orow = (size_t)(b * 1024 + qt * 64 + w * 16 + ln);
#pragma unroll
    for (int nt = 0; nt < 4; ++nt) {
      us4 o = { f2bf(acc_o[nt][0] * inv), f2bf(acc_o[nt][1] * inv),
                f2bf(acc_o[nt][2] * inv), f2bf(acc_o[nt][3] * inv) };
      *(us4*)(Ob + orow * 1024 + h * 64 + nt * 16 + g * 4) = o;
    }
  }
}

// ---------- launcher ----------
extern "C" void kernel_launch(void* const* d_in, const int* in_sizes, int n_in,
                              void* d_out, int out_size, void* d_ws, size_t ws_size,
                              hipStream_t stream) {
  (void)in_sizes; (void)n_in; (void)out_size; (void)ws_size;
  const float* x    = (const float*)d_in[0];
  const float* Wqkv = (const float*)d_in[1];
  const float* bqkv = (const float*)d_in[2];
  const float* Wout = (const float*)d_in[3];
  const float* bout = (const float*)d_in[4];

  char* ws = (char*)d_ws;
  unsigned short* xb   = (unsigned short*)(ws);                 // 16 MB  [8192][1024]
  unsigned short* Wt1  = (unsigned short*)(ws + 16777216);      //  6 MB  [3072][1024]
  unsigned short* Wt2  = (unsigned short*)(ws + 23068672);      //  2 MB  [1024][1024]
  unsigned short* qkvb = (unsigned short*)(ws + 25165824);      // 50 MB  [8192][3072]
  unsigned short* Vt   = (unsigned short*)(ws + 75497472);      // 16 MB  [128*64][1024]
  unsigned short* Ob   = (unsigned short*)(ws + 92274688);      // 16 MB  [8192][1024]

  cast4_f32_bf16<<<8192, 256, 0, stream>>>(x, xb, 8192 * 1024);
  transcast<<<dim3(96, 32), dim3(32, 8), 0, stream>>>(Wqkv, Wt1, 1024, 3072);
  transcast<<<dim3(32, 32), dim3(32, 8), 0, stream>>>(Wout, Wt2, 1024, 1024);

  gemm8p<<<dim3(32, 12), 512, 0, stream>>>(xb, Wt1, bqkv, qkvb, 8192, 3072);
  transpose_v<<<2048, 256, 0, stream>>>(qkvb, Vt);
  attn<<<1024, 256, 0, stream>>>(qkvb, Vt, Ob);
  gemm_nt<0><<<dim3(64, 8), 256, 0, stream>>>(Ob, Wt2, bout, (float*)d_out, 8192, 1024);
}